// Round 10
// baseline (794.138 us; speedup 1.0000x reference)
//
#include <hip/hip_runtime.h>
#include <cmath>

typedef unsigned short u16;
typedef unsigned int   u32;
typedef __attribute__((ext_vector_type(8))) short bf16x8;
typedef __attribute__((ext_vector_type(4))) float f32x4;
typedef __attribute__((ext_vector_type(4))) u32   u32x4;

__device__ __forceinline__ float bf2f(u16 u){
    union { u32 i; float f; } x; x.i = ((u32)u) << 16; return x.f;
}
__device__ __forceinline__ u16 f2bf(float f){
    union { float f; u32 i; } x; x.f = f;
    u32 r = x.i + 0x7fffu + ((x.i >> 16) & 1u);
    return (u16)(r >> 16);
}

// MFMA-fragment layout for composed layer weights WB (per layer, per mat 256x128):
//   element (n,k) -> tile t=n>>4, lane=((k>>3)&3)*16 + (n&15), slot kk=k>>5, e=k&7
//   linear u16 index: ((t*4 + kk)*64 + lane)*8 + e
// Stage s (0..7) of a layer = mat m=s>>2, tiles t = (s&3)*4 .. +3  -> contiguous 8192 u16.
__device__ __forceinline__ size_t frag_idx(int n, int k){
    int t = n >> 4, sl = n & 15, kk = k >> 5, g16 = (k >> 3) & 3, e = k & 7;
    return ((size_t)(t*4 + kk)*64 + g16*16 + sl)*8 + e;
}

// ---------------- graph preprocessing ----------------

__global__ void k_count(const int* __restrict__ src, const int* __restrict__ dst,
                        int* cnt, int* notsink, int* pos, int E){
    int e = blockIdx.x*256 + threadIdx.x;
    if (e < E){
        pos[e] = atomicAdd(&cnt[dst[e]], 1);
        notsink[src[e]] = 1;   // benign race: all writers store 1
    }
}

__global__ void k_scan1(const int* __restrict__ in, int* blocksum, int N){
    __shared__ int sh[256];
    int tid = threadIdx.x;
    int base = blockIdx.x*1024 + tid*4;
    int s = 0;
    for (int j=0;j<4;j++){ int i = base+j; s += (i < N) ? in[i] : 0; }
    sh[tid] = s; __syncthreads();
    for (int d=128; d>0; d>>=1){ if (tid < d) sh[tid] += sh[tid+d]; __syncthreads(); }
    if (tid == 0) blocksum[blockIdx.x] = sh[0];
}

__global__ void k_scan2(int* blocksum, int nb){
    if (threadIdx.x == 0){
        int run = 0;
        for (int i=0;i<nb;i++){ int v = blocksum[i]; blocksum[i] = run; run += v; }
    }
}

// scan3 + sink compaction (order nondeterministic; softmax pool is order-invariant)
__global__ void k_scan3(const int* __restrict__ in, const int* __restrict__ blockoff,
                        const int* __restrict__ notsink,
                        int* out, float* inv_deg, float* haspred,
                        int* sink_list, int* nsink, int N){
    __shared__ int sh[256];
    int tid = threadIdx.x;
    int base = blockIdx.x*1024 + tid*4;
    int e[4]; int s = 0;
    for (int j=0;j<4;j++){ int i = base+j; e[j] = (i < N) ? in[i] : 0; s += e[j]; }
    sh[tid] = s; __syncthreads();
    for (int d=1; d<256; d<<=1){
        int t = (tid >= d) ? sh[tid-d] : 0;
        __syncthreads();
        sh[tid] += t;
        __syncthreads();
    }
    int excl = sh[tid] - s + blockoff[blockIdx.x];
    for (int j=0;j<4;j++){
        int i = base+j;
        if (i < N){
            out[i] = excl; excl += e[j];
            inv_deg[i] = 1.0f / (float)(e[j] > 1 ? e[j] : 1);
            haspred[i] = e[j] > 0 ? 1.0f : 0.0f;
            if (notsink[i] == 0){
                int p = atomicAdd(nsink, 1);
                sink_list[p] = i;
            }
        }
    }
}

__global__ void k_place(const int* __restrict__ src, const int* __restrict__ dst,
                        const int* __restrict__ row_ptr, const int* __restrict__ pos,
                        int* csr_src, int E){
    int e = blockIdx.x*256 + threadIdx.x;
    if (e < E)
        csr_src[row_ptr[dst[e]] + pos[e]] = src[e];
}

// ---------------- weight prep ----------------
// WT_in / WT_att: f32 [k][n] -> bf16 [n][k]. WB plain halves in fragment layout.
__global__ void k_wt_plain(const float* __restrict__ W_in, const float* __restrict__ W_att,
                           const float* __restrict__ Ws, const float* __restrict__ Wn,
                           u16* WT_in, u16* WT_att, u16* WB){
    int i = blockIdx.x*256 + threadIdx.x;   // [0, 131072)
    if (i < 32768){
        const float* srcm = (i < 16384) ? W_in : W_att;
        u16* dstm = (i < 16384) ? WT_in : WT_att;
        int w = i & 16383, n = w >> 7, k = w & 127;
        dstm[n*128 + k] = f2bf(srcm[k*128 + n]);
    } else {
        int off = i - 32768;                 // [0, 98304)
        int m  = off / 49152;                // 0: from Ws, 1: from Wn
        int w  = off % 49152;
        int l  = w >> 14, ww = w & 16383;
        int n  = ww >> 7, k = ww & 127;
        const float* srcm = m ? Wn : Ws;
        u16* dstm = WB + ((size_t)l*2 + m)*32768;
        dstm[frag_idx(n, k)] = f2bf(srcm[(size_t)l*16384 + k*128 + n]);
    }
}

// Composite halves (cols 128..255) + bias composites vb1 = bs@Wg_bot, vb2 = bn@Wg_bot.
__global__ void k_wt_comp(const float* __restrict__ Ws, const float* __restrict__ Wn,
                          const float* __restrict__ Wg,
                          const float* __restrict__ bs, const float* __restrict__ bn,
                          u16* WB, float* vb){
    __shared__ float cols[2][128];
    int l = blockIdx.x / 129;
    int b = blockIdx.x % 129;
    const float* Wgb = Wg + (size_t)l*32768 + 16384;   // Wg_bot [128][128]
    int tid = threadIdx.x;
    if (b == 128){
        int n = tid & 127;
        const float* bv = (tid < 128) ? (bs + l*128) : (bn + l*128);
        float acc = 0.f;
        for (int j=0;j<128;j++) acc += bv[j] * Wgb[j*128 + n];
        vb[l*256 + (tid>>7)*128 + n] = acc;
        return;
    }
    int m  = b >> 6;            // 0: from Ws, 1: from Wn
    int n0 = (b & 63) * 2;
    int nn = tid >> 7, k = tid & 127;
    cols[tid>>7][tid&127] = Wgb[(size_t)(tid&127)*128 + n0 + (tid>>7)];
    __syncthreads();
    const float* A = (m ? Wn : Ws) + (size_t)l*16384;
    float acc = 0.f;
    for (int j=0;j<128;j++) acc += A[k*128 + j] * cols[nn][j];
    int n = n0 + nn;
    if (m == 0) acc += Wg[(size_t)l*32768 + k*128 + n];
    u16* dstm = WB + ((size_t)l*2 + m)*32768;
    dstm[frag_idx(128 + n, k)] = f2bf(acc);
}

// ---------------- shared GEMM tile machinery ----------------

__device__ __forceinline__ void stage_A_f32(const float* __restrict__ A, u16 (*lA)[136],
                                            int row0, int n_rows, int tid){
    #pragma unroll
    for (int i=0;i<4;i++){
        int c = i*256 + tid;
        int r = c >> 4, col8 = (c & 15) * 8;
        u16 o[8] = {0,0,0,0,0,0,0,0};
        if (row0 + r < n_rows){
            float4 v0 = *(const float4*)(A + (size_t)(row0 + r)*128 + col8);
            float4 v1 = *(const float4*)(A + (size_t)(row0 + r)*128 + col8 + 4);
            o[0]=f2bf(v0.x); o[1]=f2bf(v0.y); o[2]=f2bf(v0.z); o[3]=f2bf(v0.w);
            o[4]=f2bf(v1.x); o[5]=f2bf(v1.y); o[6]=f2bf(v1.z); o[7]=f2bf(v1.w);
        }
        *(u32x4*)&lA[r][col8] = *(const u32x4*)o;
    }
}

__device__ __forceinline__ void stage_B(const u16* __restrict__ BT, int Ks, int koff0,
                                        u16 (*lB)[136], int tid){
    #pragma unroll
    for (int i=0;i<8;i++){
        int c = i*256 + tid;
        int n = c >> 4, col8 = (c & 15) * 8;
        u32x4 v = *(const u32x4*)(BT + (size_t)n*Ks + koff0 + col8);
        *(u32x4*)&lB[n][col8] = v;
    }
}

__device__ __forceinline__ void mfma_tile(const u16 (*lA)[136], const u16 (*lB)[136],
                                          int wave, int lane, f32x4* acc){
    #pragma unroll
    for (int kk=0;kk<4;kk++){
        int koff = kk*32 + (lane >> 4) * 8;
        bf16x8 a = *(const bf16x8*)&lA[wave*16 + (lane & 15)][koff];
        #pragma unroll
        for (int t=0;t<8;t++){
            bf16x8 b = *(const bf16x8*)&lB[t*16 + (lane & 15)][koff];
            acc[t] = __builtin_amdgcn_mfma_f32_16x16x32_bf16(a, b, acc[t], 0, 0, 0);
        }
    }
}

// ---------------- GEMM: h0 = f32 feats @ W_in + b_in -> bf16 ----------------

__global__ __launch_bounds__(256) void k_gemm_in(
    const float* __restrict__ A, const u16* __restrict__ BT,
    const float* __restrict__ bias, u16* __restrict__ C, int n_rows)
{
    __shared__ u16 lA[64][136];
    __shared__ u16 lB[128][136];
    int tid = threadIdx.x, wave = tid >> 6, lane = tid & 63;
    int row0 = blockIdx.x * 64;
    f32x4 acc[8];
    #pragma unroll
    for (int t=0;t<8;t++) acc[t] = (f32x4){0.f,0.f,0.f,0.f};
    stage_A_f32(A, lA, row0, n_rows, tid);
    stage_B(BT, 128, 0, lB, tid);
    __syncthreads();
    mfma_tile(lA, lB, wave, lane, acc);

    int sl = lane & 15;
    int rbase = wave*16 + (lane >> 4)*4;
    float bc[8];
    #pragma unroll
    for (int t=0;t<8;t++) bc[t] = bias[t*16 + sl];
    for (int r=0;r<4;r++){
        int row = row0 + rbase + r;
        if (row >= n_rows) continue;
        #pragma unroll
        for (int t=0;t<8;t++)
            C[(size_t)row*128 + t*16 + sl] = f2bf(acc[t][r] + bc[t]);
    }
}

// -------- fused layer: k_neigh-pattern gather (into LDS) + composed GEMM --------
// Pre-barrier: each wave gathers its 16 nodes' predecessor means with the proven
// 4-nodes/16-lanes-x-16B coalesced pattern, writing bf16 means into lN (which
// ALIASES lB1 of the B double-buffer: a2 fragments are pulled into registers
// before the pipeline's first write to lB1). Then the proven 8-stage pipelined
// GEMM. bufn (50MB/layer of HBM interface traffic) is eliminated; gather and
// GEMM phases of different resident blocks overlap on the CU.

__global__ __launch_bounds__(256, 3) void k_layer(
    const u16* __restrict__ H,
    const u16* __restrict__ WB,                       // layer's 8 stages x 8192 u16
    const int* __restrict__ row_ptr, const int* __restrict__ indeg,
    const float* __restrict__ inv_deg, const int* __restrict__ csr_src,
    const float* __restrict__ bs, const float* __restrict__ bn,
    const float* __restrict__ bg,
    const float* __restrict__ vb1, const float* __restrict__ vb2,
    const float* __restrict__ gamma, const float* __restrict__ beta,
    const float* __restrict__ haspred,
    u16* __restrict__ Hb, float* __restrict__ Hf, int n_rows)
{
    __shared__ u16 lH[64][132];       // h tile for epilogue blend (padded: conflict-free)
    __shared__ u16 lB0[8192];         // B stage buffer 0 (16KB)
    __shared__ u16 lB1[8448];         // B stage buffer 1; pre-pipeline: lN[64][132]
    u16 (*lN)[132] = (u16 (*)[132])lB1;
    int tid = threadIdx.x, wave = tid >> 6, lane = tid & 63;
    int sl = lane & 15, g16 = lane >> 4;
    int row0 = blockIdx.x * 64;

    // A1 fragments in registers: row = wave*16+sl, k = kk*32 + g16*8 + 0..7
    int arow = row0 + wave*16 + sl;
    bool av = arow < n_rows;
    bf16x8 a1[4];
    #pragma unroll
    for (int kk=0;kk<4;kk++) a1[kk] = (bf16x8){0,0,0,0,0,0,0,0};
    if (av){
        #pragma unroll
        for (int kk=0;kk<4;kk++)
            a1[kk] = *(const bf16x8*)(H + (size_t)arow*128 + kk*32 + g16*8);
    }

    // B stage-0 global loads (fly during the gather)
    u32x4 st[4];
    #pragma unroll
    for (int i=0;i<4;i++)
        st[i] = *(const u32x4*)(WB + (size_t)(i*256 + tid)*8);

    // stage h tile for epilogue
    #pragma unroll
    for (int i=0;i<4;i++){
        int c = i*256 + tid;
        int r = c >> 4, col8 = (c & 15) * 8;
        u32x4 v = {0,0,0,0};
        if (row0 + r < n_rows)
            v = *(const u32x4*)(H + (size_t)(row0 + r)*128 + col8);
        *(u32x4*)&lH[r][col8] = v;
    }

    // gather: wave handles its 16 rows in 4 rounds of the k_neigh pattern
    {
        int sub = lane >> 4;   // 4 nodes per round, 16 lanes (sl) x 16B per row
        for (int q=0;q<4;q++){
            int nrow = wave*16 + q*4 + sub;
            int node = row0 + nrow;
            bool valid = node < n_rows;
            int deg   = valid ? indeg[node]   : 0;
            int start = valid ? row_ptr[node] : 0;
            float iv  = valid ? inv_deg[node] : 0.f;
            float ga[8] = {0.f,0.f,0.f,0.f,0.f,0.f,0.f,0.f};
            for (int e0 = 0; __any(e0 < deg); e0 += 16){
                int idx = 0;
                if (e0 + sl < deg) idx = csr_src[start + e0 + sl];
                int cnt = deg - e0;
                #pragma unroll
                for (int j = 0; j < 16; j++){
                    int sidx = __shfl(idx, (sub << 4) | j);
                    if (j < cnt){
                        bf16x8 v = *(const bf16x8*)(H + (size_t)sidx*128 + sl*8);
                        #pragma unroll
                        for (int t=0;t<8;t++) ga[t] += bf2f((u16)v[t]);
                    }
                }
            }
            u16 o[8];
            #pragma unroll
            for (int t=0;t<8;t++) o[t] = f2bf(ga[t]*iv);
            *(u32x4*)&lN[nrow][sl*8] = *(const u32x4*)o;
        }
    }

    f32x4 acc[16];
    #pragma unroll
    for (int t=0;t<16;t++) acc[t] = (f32x4){0.f,0.f,0.f,0.f};
    __syncthreads();   // B1: lN + lH complete

    // A2 fragments from lN (the LDS round-trip is the 16-lane -> 4-lane transpose)
    bf16x8 a2[4];
    #pragma unroll
    for (int kk=0;kk<4;kk++)
        a2[kk] = *(const bf16x8*)&lN[wave*16 + sl][kk*32 + g16*8];

    // stage-0 B into lB0 (does NOT alias lN)
    #pragma unroll
    for (int i=0;i<4;i++)
        *(u32x4*)&lB0[(i*256 + tid)*8] = st[i];
    __syncthreads();   // B2: all a2 reads done; lB0 ready; lB1/lN space reusable

    // 8 stages: s<4 use a1 (h), s>=4 use a2 (ng); stage s covers col-tiles (s&3)*4..+3
    #pragma unroll
    for (int s=0;s<8;s++){
        if (s < 7){
            const u16* sp = WB + (size_t)(s+1)*8192;
            #pragma unroll
            for (int i=0;i<4;i++)
                st[i] = *(const u32x4*)(sp + (size_t)(i*256 + tid)*8);
        }
        const u16* bp = ((s & 1) ? lB1 : lB0) + lane*8;
        #pragma unroll
        for (int j=0;j<4;j++){
            #pragma unroll
            for (int kk=0;kk<4;kk++){
                bf16x8 b = *(const bf16x8*)(bp + ((j*4 + kk) << 9));
                int ai = (s & 3)*4 + j;
                acc[ai] = __builtin_amdgcn_mfma_f32_16x16x32_bf16(
                    (s >= 4) ? a2[kk] : a1[kk], b, acc[ai], 0, 0, 0);
            }
        }
        if (s < 7){
            u16* wp = (s & 1) ? lB0 : lB1;
            #pragma unroll
            for (int i=0;i<4;i++)
                *(u32x4*)&wp[(i*256 + tid)*8] = st[i];
        }
        __syncthreads();
    }

    // epilogue: gate, blend, LayerNorm, ReLU
    int rbase = wave*16 + g16*4;
    float bM[8], bnl[8], bG[8], vb2l[8], gam[8], bet[8];
    #pragma unroll
    for (int t=0;t<8;t++){
        int c = t*16 + sl;
        bM[t] = bs[c]; bnl[t] = bn[c];
        bG[t] = bg[c] + vb1[c]; vb2l[t] = vb2[c];
        gam[t] = gamma[c]; bet[t] = beta[c];
    }
    if (Hf){
        // last layer: f32 output only (full 64B lines per (r,t) store)
        for (int r=0;r<4;r++){
            int row = row0 + rbase + r;
            if (row >= n_rows) continue;   // quad-uniform
            float hp = haspred[row];
            float v[8], s = 0.f;
            #pragma unroll
            for (int t=0;t<8;t++){
                int c = t*16 + sl;
                float m = acc[t][r]   + bM[t] + hp*bnl[t];
                float x = acc[t+8][r] + bG[t] + hp*vb2l[t];
                float gg = 1.f/(1.f + expf(-x));
                float hv = bf2f(lH[rbase + r][c]);
                v[t] = gg*m + (1.f - gg)*hv;
                s += v[t];
            }
            s += __shfl_xor(s,1); s += __shfl_xor(s,2); s += __shfl_xor(s,4); s += __shfl_xor(s,8);
            float mu = s * (1.f/128.f);
            float q = 0.f;
            #pragma unroll
            for (int t=0;t<8;t++){ float d = v[t]-mu; q += d*d; }
            q += __shfl_xor(q,1); q += __shfl_xor(q,2); q += __shfl_xor(q,4); q += __shfl_xor(q,8);
            float rs = rsqrtf(q*(1.f/128.f) + 1e-5f);
            #pragma unroll
            for (int t=0;t<8;t++){
                float o = (v[t]-mu)*rs*gam[t] + bet[t];
                Hf[(size_t)row*128 + t*16 + sl] = o > 0.f ? o : 0.f;
            }
        }
    } else {
        // intermediate layer: bf16 output, vectorized via lH round-trip
        float ov[4][8];
        for (int r=0;r<4;r++){
            int row = row0 + rbase + r;
            float hp = (row < n_rows) ? haspred[row] : 0.f;
            float v[8], s = 0.f;
            #pragma unroll
            for (int t=0;t<8;t++){
                int c = t*16 + sl;
                float m = acc[t][r]   + bM[t] + hp*bnl[t];
                float x = acc[t+8][r] + bG[t] + hp*vb2l[t];
                float gg = 1.f/(1.f + expf(-x));
                float hv = bf2f(lH[rbase + r][c]);
                v[t] = gg*m + (1.f - gg)*hv;
                s += v[t];
            }
            s += __shfl_xor(s,1); s += __shfl_xor(s,2); s += __shfl_xor(s,4); s += __shfl_xor(s,8);
            float mu = s * (1.f/128.f);
            float q = 0.f;
            #pragma unroll
            for (int t=0;t<8;t++){ float d = v[t]-mu; q += d*d; }
            q += __shfl_xor(q,1); q += __shfl_xor(q,2); q += __shfl_xor(q,4); q += __shfl_xor(q,8);
            float rs = rsqrtf(q*(1.f/128.f) + 1e-5f);
            #pragma unroll
            for (int t=0;t<8;t++){
                float o = (v[t]-mu)*rs*gam[t] + bet[t];
                ov[r][t] = o > 0.f ? o : 0.f;
            }
        }
        __syncthreads();   // all lH blend-reads complete
        #pragma unroll
        for (int r=0;r<4;r++)
            #pragma unroll
            for (int t=0;t<8;t++)
                lH[rbase + r][t*16 + sl] = f2bf(ov[r][t]);
        __syncthreads();
        #pragma unroll
        for (int i=0;i<4;i++){
            int c = i*256 + tid;
            int r = c >> 4, col8 = (c & 15) * 8;
            if (row0 + r < n_rows)
                *(u32x4*)&Hb[(size_t)(row0 + r)*128 + col8] = *(const u32x4*)&lH[r][col8];
        }
    }
}

// ------- attention scores on SINK ROWS ONLY (h read as f32 from d_out) -------

__global__ __launch_bounds__(256) void k_att_sink(
    const float* __restrict__ Hf, const u16* __restrict__ BT,
    const float* __restrict__ b_att, const float* __restrict__ Wsc,
    const float* __restrict__ bsc, const int* __restrict__ sink_list,
    const int* __restrict__ nsink, float* __restrict__ scores_sink)
{
    __shared__ u16 lA[64][136];
    __shared__ u16 lB[128][136];
    int ns = *nsink;
    int tid = threadIdx.x, wave = tid >> 6, lane = tid & 63;
    int sl = lane & 15;
    stage_B(BT, 128, 0, lB, tid);
    float bac[8], wc[8];
    #pragma unroll
    for (int t=0;t<8;t++){ bac[t] = b_att[t*16 + sl]; wc[t] = Wsc[t*16 + sl]; }
    float b0 = bsc[0];
    int rbase = wave*16 + (lane >> 4)*4;

    for (int c0 = blockIdx.x*64; c0 < ns; c0 += gridDim.x*64){
        __syncthreads();   // lA reuse fence (also covers initial lB stage)
        #pragma unroll
        for (int i=0;i<4;i++){
            int c = i*256 + tid;
            int r = c >> 4, col8 = (c & 15) * 8;
            u16 o[8] = {0,0,0,0,0,0,0,0};
            if (c0 + r < ns){
                int row = sink_list[c0 + r];
                float4 v0 = *(const float4*)(Hf + (size_t)row*128 + col8);
                float4 v1 = *(const float4*)(Hf + (size_t)row*128 + col8 + 4);
                o[0]=f2bf(v0.x); o[1]=f2bf(v0.y); o[2]=f2bf(v0.z); o[3]=f2bf(v0.w);
                o[4]=f2bf(v1.x); o[5]=f2bf(v1.y); o[6]=f2bf(v1.z); o[7]=f2bf(v1.w);
            }
            *(u32x4*)&lA[r][col8] = *(const u32x4*)o;
        }
        __syncthreads();
        f32x4 acc[8];
        #pragma unroll
        for (int t=0;t<8;t++) acc[t] = (f32x4){0.f,0.f,0.f,0.f};
        mfma_tile(lA, lB, wave, lane, acc);

        for (int r=0;r<4;r++){
            int i = c0 + rbase + r;
            if (i >= ns) continue;
            float p = 0.f;
            #pragma unroll
            for (int t=0;t<8;t++) p += tanhf(acc[t][r] + bac[t]) * wc[t];
            p += __shfl_xor(p,1); p += __shfl_xor(p,2); p += __shfl_xor(p,4); p += __shfl_xor(p,8);
            if (sl == 0)
                scores_sink[i] = p + b0;
        }
    }
}

// ------------- softmax-pool over compacted sinks (h read as f32) -------------

__global__ void k_pool_sink(const float* __restrict__ Hf, const int* __restrict__ sink_list,
                            const int* __restrict__ nsink,
                            const float* __restrict__ scores_sink,
                            float* __restrict__ out){
    __shared__ float sh[256];
    __shared__ float swg[2];
    int ns = *nsink;
    int tid = threadIdx.x;
    int col = tid & 127, grp = tid >> 7;
    float acc = 0.f, wsum = 0.f;
    for (int i = grp; i < ns; i += 2){
        float w = expf(scores_sink[i]);
        acc += w * Hf[(size_t)sink_list[i]*128 + col];
        if (col == 0) wsum += w;
    }
    sh[tid] = acc;
    if (col == 0) swg[grp] = wsum;
    __syncthreads();
    if (tid < 128) out[tid] = (sh[tid] + sh[tid+128]) / (swg[0] + swg[1]);
}

// ---------------- host launch ----------------

extern "C" void kernel_launch(void* const* d_in, const int* in_sizes, int n_in,
                              void* d_out, int out_size, void* d_ws, size_t ws_size,
                              hipStream_t stream)
{
    const float* node_feats = (const float*)d_in[0];
    const int* src     = (const int*)d_in[1];
    const int* dst     = (const int*)d_in[2];
    const float* W_in    = (const float*)d_in[3];
    const float* b_in    = (const float*)d_in[4];
    const float* Ws      = (const float*)d_in[5];
    const float* bs      = (const float*)d_in[6];
    const float* Wn      = (const float*)d_in[7];
    const float* bn      = (const float*)d_in[8];
    const float* Wg      = (const float*)d_in[9];
    const float* bg      = (const float*)d_in[10];
    const float* gamma   = (const float*)d_in[11];
    const float* beta    = (const float*)d_in[12];
    const float* W_att   = (const float*)d_in[13];
    const float* b_att   = (const float*)d_in[14];
    const float* W_score = (const float*)d_in[15];
    const float* b_score = (const float*)d_in[16];

    const int N = in_sizes[0] / 128;
    const int E = in_sizes[1];

    char* w = (char*)d_ws;
    auto alloc = [&](size_t bytes)->char* {
        char* p = w; w += (bytes + 255) & ~(size_t)255; return p;
    };
    u16* WT_in  = (u16*)alloc(128*128*2);
    u16* WT_att = (u16*)alloc(128*128*2);
    u16* WB     = (u16*)alloc(3*2*256*128*2);   // 3 layers x (WB1,WB2) fragment layout
    float* vb   = (float*)alloc(3*256*4);
    // zeroed region: cnt, notsink, nsink (contiguous)
    int* cnt      = (int*)alloc((size_t)N*4);
    int* notsink  = (int*)alloc((size_t)N*4);
    int* nsink    = (int*)alloc(256);
    size_t zero_bytes = (size_t)((char*)nsink + 256 - (char*)cnt);
    int* pos      = (int*)alloc((size_t)E*4);
    int* row_ptr  = (int*)alloc((size_t)N*4);
    int* blocksum = (int*)alloc(1024*4);
    int* csr_src  = (int*)alloc((size_t)E*4);
    float* inv_deg = (float*)alloc((size_t)N*4);
    float* haspred = (float*)alloc((size_t)N*4);
    int* sink_list = (int*)alloc((size_t)N*4);
    float* scores_sink = (float*)alloc((size_t)N*4);
    u16* buf0 = (u16*)alloc((size_t)N*128*2);   // h ping
    u16* buf1 = (u16*)alloc((size_t)N*128*2);   // h pong

    float* h_out   = (float*)d_out;
    float* emb_out = h_out + (size_t)N*128;

    hipMemsetAsync(cnt, 0, zero_bytes, stream);

    k_wt_plain<<<512, 256, 0, stream>>>(W_in, W_att, Ws, Wn, WT_in, WT_att, WB);
    k_wt_comp<<<3*129, 256, 0, stream>>>(Ws, Wn, Wg, bs, bn, WB, vb);

    k_count<<<(E+255)/256, 256, 0, stream>>>(src, dst, cnt, notsink, pos, E);

    int nb = (N + 1023) / 1024;
    k_scan1<<<nb, 256, 0, stream>>>(cnt, blocksum, N);
    k_scan2<<<1, 256, 0, stream>>>(blocksum, nb);
    k_scan3<<<nb, 256, 0, stream>>>(cnt, blocksum, notsink, row_ptr, inv_deg, haspred,
                                    sink_list, nsink, N);
    k_place<<<(E+255)/256, 256, 0, stream>>>(src, dst, row_ptr, pos, csr_src, E);

    int gblk = (N + 63) / 64;

    k_gemm_in<<<gblk, 256, 0, stream>>>(node_feats, WT_in, b_in, buf0, N);

    u16* hin = buf0;
    for (int i=0;i<3;i++){
        u16* hb  = (hin == buf0) ? buf1 : buf0;
        float* hf = (i == 2) ? h_out : nullptr;
        k_layer<<<gblk, 256, 0, stream>>>(hin,
                                          WB + (size_t)i*65536,
                                          row_ptr, cnt, inv_deg, csr_src,
                                          bs + i*128, bn + i*128, bg + i*128,
                                          vb + i*256, vb + i*256 + 128,
                                          gamma + i*128, beta + i*128, haspred,
                                          hb, hf, N);
        hin = hb;
    }

    k_att_sink<<<8, 256, 0, stream>>>(h_out, WT_att, b_att, W_score, b_score,
                                      sink_list, nsink, scores_sink);
    k_pool_sink<<<1, 256, 0, stream>>>(h_out, sink_list, nsink, scores_sink, emb_out);

    (void)n_in; (void)out_size; (void)ws_size;
}

// Round 11
// 533.419 us; speedup vs baseline: 1.4888x; 1.4888x over previous
//
#include <hip/hip_runtime.h>
#include <cmath>

typedef unsigned short u16;
typedef unsigned int   u32;
typedef __attribute__((ext_vector_type(8))) short bf16x8;
typedef __attribute__((ext_vector_type(4))) float f32x4;
typedef __attribute__((ext_vector_type(4))) u32   u32x4;

__device__ __forceinline__ float bf2f(u16 u){
    union { u32 i; float f; } x; x.i = ((u32)u) << 16; return x.f;
}
__device__ __forceinline__ u16 f2bf(float f){
    union { float f; u32 i; } x; x.f = f;
    u32 r = x.i + 0x7fffu + ((x.i >> 16) & 1u);
    return (u16)(r >> 16);
}

// MFMA-fragment layout for composed layer weights WB (per layer, per mat 256x128):
//   element (n,k) -> tile t=n>>4, lane=((k>>3)&3)*16 + (n&15), slot kk=k>>5, e=k&7
//   linear u16 index: ((t*4 + kk)*64 + lane)*8 + e
// Stage s (0..7) of a layer = mat m=s>>2, tiles t = (s&3)*4 .. +3  -> contiguous 8192 u16.
__device__ __forceinline__ size_t frag_idx(int n, int k){
    int t = n >> 4, sl = n & 15, kk = k >> 5, g16 = (k >> 3) & 3, e = k & 7;
    return ((size_t)(t*4 + kk)*64 + g16*16 + sl)*8 + e;
}

// ---------------- graph preprocessing ----------------

__global__ void k_count(const int* __restrict__ src, const int* __restrict__ dst,
                        int* cnt, int* notsink, int* pos, int E){
    int e = blockIdx.x*256 + threadIdx.x;
    if (e < E){
        pos[e] = atomicAdd(&cnt[dst[e]], 1);
        notsink[src[e]] = 1;   // benign race: all writers store 1
    }
}

__global__ void k_scan1(const int* __restrict__ in, int* blocksum, int N){
    __shared__ int sh[256];
    int tid = threadIdx.x;
    int base = blockIdx.x*1024 + tid*4;
    int s = 0;
    for (int j=0;j<4;j++){ int i = base+j; s += (i < N) ? in[i] : 0; }
    sh[tid] = s; __syncthreads();
    for (int d=128; d>0; d>>=1){ if (tid < d) sh[tid] += sh[tid+d]; __syncthreads(); }
    if (tid == 0) blocksum[blockIdx.x] = sh[0];
}

__global__ void k_scan2(int* blocksum, int nb){
    if (threadIdx.x == 0){
        int run = 0;
        for (int i=0;i<nb;i++){ int v = blocksum[i]; blocksum[i] = run; run += v; }
    }
}

// scan3 + sink compaction (order nondeterministic; softmax pool is order-invariant)
__global__ void k_scan3(const int* __restrict__ in, const int* __restrict__ blockoff,
                        const int* __restrict__ notsink,
                        int* out, float* inv_deg, float* haspred,
                        int* sink_list, int* nsink, int N){
    __shared__ int sh[256];
    int tid = threadIdx.x;
    int base = blockIdx.x*1024 + tid*4;
    int e[4]; int s = 0;
    for (int j=0;j<4;j++){ int i = base+j; e[j] = (i < N) ? in[i] : 0; s += e[j]; }
    sh[tid] = s; __syncthreads();
    for (int d=1; d<256; d<<=1){
        int t = (tid >= d) ? sh[tid-d] : 0;
        __syncthreads();
        sh[tid] += t;
        __syncthreads();
    }
    int excl = sh[tid] - s + blockoff[blockIdx.x];
    for (int j=0;j<4;j++){
        int i = base+j;
        if (i < N){
            out[i] = excl; excl += e[j];
            inv_deg[i] = 1.0f / (float)(e[j] > 1 ? e[j] : 1);
            haspred[i] = e[j] > 0 ? 1.0f : 0.0f;
            if (notsink[i] == 0){
                int p = atomicAdd(nsink, 1);
                sink_list[p] = i;
            }
        }
    }
}

__global__ void k_place(const int* __restrict__ src, const int* __restrict__ dst,
                        const int* __restrict__ row_ptr, const int* __restrict__ pos,
                        int* csr_src, int E){
    int e = blockIdx.x*256 + threadIdx.x;
    if (e < E)
        csr_src[row_ptr[dst[e]] + pos[e]] = src[e];
}

// ---------------- weight prep ----------------
// WT_in / WT_att: f32 [k][n] -> bf16 [n][k]. WB plain halves in fragment layout.
__global__ void k_wt_plain(const float* __restrict__ W_in, const float* __restrict__ W_att,
                           const float* __restrict__ Ws, const float* __restrict__ Wn,
                           u16* WT_in, u16* WT_att, u16* WB){
    int i = blockIdx.x*256 + threadIdx.x;   // [0, 131072)
    if (i < 32768){
        const float* srcm = (i < 16384) ? W_in : W_att;
        u16* dstm = (i < 16384) ? WT_in : WT_att;
        int w = i & 16383, n = w >> 7, k = w & 127;
        dstm[n*128 + k] = f2bf(srcm[k*128 + n]);
    } else {
        int off = i - 32768;                 // [0, 98304)
        int m  = off / 49152;                // 0: from Ws, 1: from Wn
        int w  = off % 49152;
        int l  = w >> 14, ww = w & 16383;
        int n  = ww >> 7, k = ww & 127;
        const float* srcm = m ? Wn : Ws;
        u16* dstm = WB + ((size_t)l*2 + m)*32768;
        dstm[frag_idx(n, k)] = f2bf(srcm[(size_t)l*16384 + k*128 + n]);
    }
}

// Composite halves (cols 128..255) + bias composites vb1 = bs@Wg_bot, vb2 = bn@Wg_bot.
__global__ void k_wt_comp(const float* __restrict__ Ws, const float* __restrict__ Wn,
                          const float* __restrict__ Wg,
                          const float* __restrict__ bs, const float* __restrict__ bn,
                          u16* WB, float* vb){
    __shared__ float cols[2][128];
    int l = blockIdx.x / 129;
    int b = blockIdx.x % 129;
    const float* Wgb = Wg + (size_t)l*32768 + 16384;   // Wg_bot [128][128]
    int tid = threadIdx.x;
    if (b == 128){
        int n = tid & 127;
        const float* bv = (tid < 128) ? (bs + l*128) : (bn + l*128);
        float acc = 0.f;
        for (int j=0;j<128;j++) acc += bv[j] * Wgb[j*128 + n];
        vb[l*256 + (tid>>7)*128 + n] = acc;
        return;
    }
    int m  = b >> 6;            // 0: from Ws, 1: from Wn
    int n0 = (b & 63) * 2;
    int nn = tid >> 7, k = tid & 127;
    cols[tid>>7][tid&127] = Wgb[(size_t)(tid&127)*128 + n0 + (tid>>7)];
    __syncthreads();
    const float* A = (m ? Wn : Ws) + (size_t)l*16384;
    float acc = 0.f;
    for (int j=0;j<128;j++) acc += A[k*128 + j] * cols[nn][j];
    int n = n0 + nn;
    if (m == 0) acc += Wg[(size_t)l*32768 + k*128 + n];
    u16* dstm = WB + ((size_t)l*2 + m)*32768;
    dstm[frag_idx(128 + n, k)] = f2bf(acc);
}

// ---------------- neighbor mean: 4 nodes/wave, 16 lanes x 16B per row ----------------

__global__ void k_neigh(const u16* __restrict__ h, const int* __restrict__ row_ptr,
                        const int* __restrict__ indeg, const float* __restrict__ inv_deg,
                        const int* __restrict__ csr_src, u16* __restrict__ neigh, int N){
    int wid  = (blockIdx.x*256 + threadIdx.x) >> 6;
    int lane = threadIdx.x & 63;
    int sub = lane >> 4, sl = lane & 15;
    int node = wid*4 + sub;
    bool valid = node < N;
    int deg   = valid ? indeg[node]   : 0;
    int start = valid ? row_ptr[node] : 0;
    float acc[8] = {0.f,0.f,0.f,0.f,0.f,0.f,0.f,0.f};
    for (int e0 = 0; __any(e0 < deg); e0 += 16){
        int idx = 0;
        if (e0 + sl < deg) idx = csr_src[start + e0 + sl];
        int cnt = deg - e0;
        #pragma unroll
        for (int j = 0; j < 16; j++){
            int sidx = __shfl(idx, (sub << 4) | j);
            if (j < cnt){
                bf16x8 v = *(const bf16x8*)(h + (size_t)sidx*128 + sl*8);
                #pragma unroll
                for (int t=0;t<8;t++) acc[t] += bf2f((u16)v[t]);
            }
        }
    }
    if (valid){
        float iv = inv_deg[node];
        u16 o[8];
        #pragma unroll
        for (int t=0;t<8;t++) o[t] = f2bf(acc[t]*iv);
        *(u32x4*)(neigh + (size_t)node*128 + sl*8) = *(const u32x4*)o;
    }
}

// ---------------- shared GEMM tile machinery ----------------

__device__ __forceinline__ void stage_A_f32(const float* __restrict__ A, u16 (*lA)[136],
                                            int row0, int n_rows, int tid){
    #pragma unroll
    for (int i=0;i<4;i++){
        int c = i*256 + tid;
        int r = c >> 4, col8 = (c & 15) * 8;
        u16 o[8] = {0,0,0,0,0,0,0,0};
        if (row0 + r < n_rows){
            float4 v0 = *(const float4*)(A + (size_t)(row0 + r)*128 + col8);
            float4 v1 = *(const float4*)(A + (size_t)(row0 + r)*128 + col8 + 4);
            o[0]=f2bf(v0.x); o[1]=f2bf(v0.y); o[2]=f2bf(v0.z); o[3]=f2bf(v0.w);
            o[4]=f2bf(v1.x); o[5]=f2bf(v1.y); o[6]=f2bf(v1.z); o[7]=f2bf(v1.w);
        }
        *(u32x4*)&lA[r][col8] = *(const u32x4*)o;
    }
}

__device__ __forceinline__ void stage_B(const u16* __restrict__ BT, int Ks, int koff0,
                                        u16 (*lB)[136], int tid){
    #pragma unroll
    for (int i=0;i<8;i++){
        int c = i*256 + tid;
        int n = c >> 4, col8 = (c & 15) * 8;
        u32x4 v = *(const u32x4*)(BT + (size_t)n*Ks + koff0 + col8);
        *(u32x4*)&lB[n][col8] = v;
    }
}

__device__ __forceinline__ void mfma_tile(const u16 (*lA)[136], const u16 (*lB)[136],
                                          int wave, int lane, f32x4* acc){
    #pragma unroll
    for (int kk=0;kk<4;kk++){
        int koff = kk*32 + (lane >> 4) * 8;
        bf16x8 a = *(const bf16x8*)&lA[wave*16 + (lane & 15)][koff];
        #pragma unroll
        for (int t=0;t<8;t++){
            bf16x8 b = *(const bf16x8*)&lB[t*16 + (lane & 15)][koff];
            acc[t] = __builtin_amdgcn_mfma_f32_16x16x32_bf16(a, b, acc[t], 0, 0, 0);
        }
    }
}

// ---------------- GEMM: h0 = f32 feats @ W_in + b_in -> bf16 ----------------
// Output vectorized via lA round-trip (transpose write is a 2-way bank alias = free).

__global__ __launch_bounds__(256) void k_gemm_in(
    const float* __restrict__ A, const u16* __restrict__ BT,
    const float* __restrict__ bias, u16* __restrict__ C, int n_rows)
{
    __shared__ u16 lA[64][136];
    __shared__ u16 lB[128][136];
    int tid = threadIdx.x, wave = tid >> 6, lane = tid & 63;
    int row0 = blockIdx.x * 64;
    f32x4 acc[8];
    #pragma unroll
    for (int t=0;t<8;t++) acc[t] = (f32x4){0.f,0.f,0.f,0.f};
    stage_A_f32(A, lA, row0, n_rows, tid);
    stage_B(BT, 128, 0, lB, tid);
    __syncthreads();
    mfma_tile(lA, lB, wave, lane, acc);

    int sl = lane & 15;
    int rbase = wave*16 + (lane >> 4)*4;
    float bc[8];
    #pragma unroll
    for (int t=0;t<8;t++) bc[t] = bias[t*16 + sl];
    __syncthreads();   // all lA reads (mfma) complete before overwrite
    #pragma unroll
    for (int r=0;r<4;r++)
        #pragma unroll
        for (int t=0;t<8;t++)
            lA[rbase + r][t*16 + sl] = f2bf(acc[t][r] + bc[t]);
    __syncthreads();
    #pragma unroll
    for (int i=0;i<4;i++){
        int c = i*256 + tid;
        int r = c >> 4, col8 = (c & 15) * 8;
        if (row0 + r < n_rows)
            *(u32x4*)&C[(size_t)(row0 + r)*128 + col8] = *(const u32x4*)&lA[r][col8];
    }
}

// -------- fused layer (round-3 proven structure), composed single-GEMM, --------
// -------- pipelined LDS-staged B; output: f32-only (last) / vectorized bf16 ----

__global__ __launch_bounds__(256, 3) void k_layer(
    const u16* __restrict__ H, const u16* __restrict__ Ng,
    const u16* __restrict__ WB,                       // layer's 8 stages x 8192 u16
    const float* __restrict__ bs, const float* __restrict__ bn,
    const float* __restrict__ bg,
    const float* __restrict__ vb1, const float* __restrict__ vb2,
    const float* __restrict__ gamma, const float* __restrict__ beta,
    const float* __restrict__ haspred,
    u16* __restrict__ Hb, float* __restrict__ Hf, int n_rows)
{
    __shared__ u16 lH[64][132];       // h tile for epilogue blend (padded: conflict-free)
    __shared__ u16 lB[2][8192];       // B fragment double buffer (16KB each)
    int tid = threadIdx.x, wave = tid >> 6, lane = tid & 63;
    int sl = lane & 15, g16 = lane >> 4;
    int row0 = blockIdx.x * 64;

    // A fragments in registers: row = wave*16+sl, k = kk*32 + g16*8 + 0..7
    int arow = row0 + wave*16 + sl;
    bool av = arow < n_rows;
    bf16x8 a1[4], a2[4];
    #pragma unroll
    for (int kk=0;kk<4;kk++){
        a1[kk] = (bf16x8){0,0,0,0,0,0,0,0};
        a2[kk] = (bf16x8){0,0,0,0,0,0,0,0};
    }
    if (av){
        #pragma unroll
        for (int kk=0;kk<4;kk++){
            a1[kk] = *(const bf16x8*)(H  + (size_t)arow*128 + kk*32 + g16*8);
            a2[kk] = *(const bf16x8*)(Ng + (size_t)arow*128 + kk*32 + g16*8);
        }
    }

    // stage h tile for epilogue
    #pragma unroll
    for (int i=0;i<4;i++){
        int c = i*256 + tid;
        int r = c >> 4, col8 = (c & 15) * 8;
        u32x4 v = {0,0,0,0};
        if (row0 + r < n_rows)
            v = *(const u32x4*)(H + (size_t)(row0 + r)*128 + col8);
        *(u32x4*)&lH[r][col8] = v;
    }

    // stage 0 of B
    u32x4 st[4];
    #pragma unroll
    for (int i=0;i<4;i++)
        st[i] = *(const u32x4*)(WB + (size_t)(i*256 + tid)*8);
    #pragma unroll
    for (int i=0;i<4;i++)
        *(u32x4*)&lB[0][(i*256 + tid)*8] = st[i];

    f32x4 acc[16];
    #pragma unroll
    for (int t=0;t<16;t++) acc[t] = (f32x4){0.f,0.f,0.f,0.f};
    __syncthreads();

    // 8 stages: s<4 use a1 (h), s>=4 use a2 (ng); stage s covers col-tiles (s&3)*4..+3
    #pragma unroll
    for (int s=0;s<8;s++){
        int cur = s & 1;
        if (s < 7){
            const u16* sp = WB + (size_t)(s+1)*8192;
            #pragma unroll
            for (int i=0;i<4;i++)
                st[i] = *(const u32x4*)(sp + (size_t)(i*256 + tid)*8);
        }
        const u16* bp = &lB[cur][lane*8];
        #pragma unroll
        for (int j=0;j<4;j++){
            #pragma unroll
            for (int kk=0;kk<4;kk++){
                bf16x8 b = *(const bf16x8*)(bp + ((j*4 + kk) << 9));
                int ai = (s & 3)*4 + j;
                acc[ai] = __builtin_amdgcn_mfma_f32_16x16x32_bf16(
                    (s >= 4) ? a2[kk] : a1[kk], b, acc[ai], 0, 0, 0);
            }
        }
        if (s < 7){
            #pragma unroll
            for (int i=0;i<4;i++)
                *(u32x4*)&lB[cur ^ 1][(i*256 + tid)*8] = st[i];
        }
        __syncthreads();
    }

    // epilogue: gate, blend, LayerNorm, ReLU
    int rbase = wave*16 + g16*4;
    float bM[8], bnl[8], bG[8], vb2l[8], gam[8], bet[8];
    #pragma unroll
    for (int t=0;t<8;t++){
        int c = t*16 + sl;
        bM[t] = bs[c]; bnl[t] = bn[c];
        bG[t] = bg[c] + vb1[c]; vb2l[t] = vb2[c];
        gam[t] = gamma[c]; bet[t] = beta[c];
    }
    if (Hf){
        // last layer: f32 output only (full 64B lines per (r,t) store)
        for (int r=0;r<4;r++){
            int row = row0 + rbase + r;
            if (row >= n_rows) continue;   // quad-uniform
            float hp = haspred[row];
            float v[8], s = 0.f;
            #pragma unroll
            for (int t=0;t<8;t++){
                int c = t*16 + sl;
                float m = acc[t][r]   + bM[t] + hp*bnl[t];
                float x = acc[t+8][r] + bG[t] + hp*vb2l[t];
                float gg = 1.f/(1.f + expf(-x));
                float hv = bf2f(lH[rbase + r][c]);
                v[t] = gg*m + (1.f - gg)*hv;
                s += v[t];
            }
            s += __shfl_xor(s,1); s += __shfl_xor(s,2); s += __shfl_xor(s,4); s += __shfl_xor(s,8);
            float mu = s * (1.f/128.f);
            float q = 0.f;
            #pragma unroll
            for (int t=0;t<8;t++){ float d = v[t]-mu; q += d*d; }
            q += __shfl_xor(q,1); q += __shfl_xor(q,2); q += __shfl_xor(q,4); q += __shfl_xor(q,8);
            float rs = rsqrtf(q*(1.f/128.f) + 1e-5f);
            #pragma unroll
            for (int t=0;t<8;t++){
                float o = (v[t]-mu)*rs*gam[t] + bet[t];
                Hf[(size_t)row*128 + t*16 + sl] = o > 0.f ? o : 0.f;
            }
        }
    } else {
        // intermediate layer: bf16 output, vectorized via lH round-trip
        float ov[4][8];
        for (int r=0;r<4;r++){
            int row = row0 + rbase + r;
            float hp = (row < n_rows) ? haspred[row] : 0.f;
            float v[8], s = 0.f;
            #pragma unroll
            for (int t=0;t<8;t++){
                int c = t*16 + sl;
                float m = acc[t][r]   + bM[t] + hp*bnl[t];
                float x = acc[t+8][r] + bG[t] + hp*vb2l[t];
                float gg = 1.f/(1.f + expf(-x));
                float hv = bf2f(lH[rbase + r][c]);
                v[t] = gg*m + (1.f - gg)*hv;
                s += v[t];
            }
            s += __shfl_xor(s,1); s += __shfl_xor(s,2); s += __shfl_xor(s,4); s += __shfl_xor(s,8);
            float mu = s * (1.f/128.f);
            float q = 0.f;
            #pragma unroll
            for (int t=0;t<8;t++){ float d = v[t]-mu; q += d*d; }
            q += __shfl_xor(q,1); q += __shfl_xor(q,2); q += __shfl_xor(q,4); q += __shfl_xor(q,8);
            float rs = rsqrtf(q*(1.f/128.f) + 1e-5f);
            #pragma unroll
            for (int t=0;t<8;t++){
                float o = (v[t]-mu)*rs*gam[t] + bet[t];
                ov[r][t] = o > 0.f ? o : 0.f;
            }
        }
        __syncthreads();   // all lH blend-reads complete
        #pragma unroll
        for (int r=0;r<4;r++)
            #pragma unroll
            for (int t=0;t<8;t++)
                lH[rbase + r][t*16 + sl] = f2bf(ov[r][t]);
        __syncthreads();
        #pragma unroll
        for (int i=0;i<4;i++){
            int c = i*256 + tid;
            int r = c >> 4, col8 = (c & 15) * 8;
            if (row0 + r < n_rows)
                *(u32x4*)&Hb[(size_t)(row0 + r)*128 + col8] = *(const u32x4*)&lH[r][col8];
        }
    }
}

// ------- attention scores on SINK ROWS ONLY (h read as f32 from d_out) -------

__global__ __launch_bounds__(256) void k_att_sink(
    const float* __restrict__ Hf, const u16* __restrict__ BT,
    const float* __restrict__ b_att, const float* __restrict__ Wsc,
    const float* __restrict__ bsc, const int* __restrict__ sink_list,
    const int* __restrict__ nsink, float* __restrict__ scores_sink)
{
    __shared__ u16 lA[64][136];
    __shared__ u16 lB[128][136];
    int ns = *nsink;
    int tid = threadIdx.x, wave = tid >> 6, lane = tid & 63;
    int sl = lane & 15;
    stage_B(BT, 128, 0, lB, tid);
    float bac[8], wc[8];
    #pragma unroll
    for (int t=0;t<8;t++){ bac[t] = b_att[t*16 + sl]; wc[t] = Wsc[t*16 + sl]; }
    float b0 = bsc[0];
    int rbase = wave*16 + (lane >> 4)*4;

    for (int c0 = blockIdx.x*64; c0 < ns; c0 += gridDim.x*64){
        __syncthreads();   // lA reuse fence (also covers initial lB stage)
        #pragma unroll
        for (int i=0;i<4;i++){
            int c = i*256 + tid;
            int r = c >> 4, col8 = (c & 15) * 8;
            u16 o[8] = {0,0,0,0,0,0,0,0};
            if (c0 + r < ns){
                int row = sink_list[c0 + r];
                float4 v0 = *(const float4*)(Hf + (size_t)row*128 + col8);
                float4 v1 = *(const float4*)(Hf + (size_t)row*128 + col8 + 4);
                o[0]=f2bf(v0.x); o[1]=f2bf(v0.y); o[2]=f2bf(v0.z); o[3]=f2bf(v0.w);
                o[4]=f2bf(v1.x); o[5]=f2bf(v1.y); o[6]=f2bf(v1.z); o[7]=f2bf(v1.w);
            }
            *(u32x4*)&lA[r][col8] = *(const u32x4*)o;
        }
        __syncthreads();
        f32x4 acc[8];
        #pragma unroll
        for (int t=0;t<8;t++) acc[t] = (f32x4){0.f,0.f,0.f,0.f};
        mfma_tile(lA, lB, wave, lane, acc);

        for (int r=0;r<4;r++){
            int i = c0 + rbase + r;
            if (i >= ns) continue;
            float p = 0.f;
            #pragma unroll
            for (int t=0;t<8;t++) p += tanhf(acc[t][r] + bac[t]) * wc[t];
            p += __shfl_xor(p,1); p += __shfl_xor(p,2); p += __shfl_xor(p,4); p += __shfl_xor(p,8);
            if (sl == 0)
                scores_sink[i] = p + b0;
        }
    }
}

// ------------- softmax-pool over compacted sinks (h read as f32) -------------

__global__ void k_pool_sink(const float* __restrict__ Hf, const int* __restrict__ sink_list,
                            const int* __restrict__ nsink,
                            const float* __restrict__ scores_sink,
                            float* __restrict__ out){
    __shared__ float sh[256];
    __shared__ float swg[2];
    int ns = *nsink;
    int tid = threadIdx.x;
    int col = tid & 127, grp = tid >> 7;
    float acc = 0.f, wsum = 0.f;
    for (int i = grp; i < ns; i += 2){
        float w = expf(scores_sink[i]);
        acc += w * Hf[(size_t)sink_list[i]*128 + col];
        if (col == 0) wsum += w;
    }
    sh[tid] = acc;
    if (col == 0) swg[grp] = wsum;
    __syncthreads();
    if (tid < 128) out[tid] = (sh[tid] + sh[tid+128]) / (swg[0] + swg[1]);
}

// ---------------- host launch ----------------

extern "C" void kernel_launch(void* const* d_in, const int* in_sizes, int n_in,
                              void* d_out, int out_size, void* d_ws, size_t ws_size,
                              hipStream_t stream)
{
    const float* node_feats = (const float*)d_in[0];
    const int* src     = (const int*)d_in[1];
    const int* dst     = (const int*)d_in[2];
    const float* W_in    = (const float*)d_in[3];
    const float* b_in    = (const float*)d_in[4];
    const float* Ws      = (const float*)d_in[5];
    const float* bs      = (const float*)d_in[6];
    const float* Wn      = (const float*)d_in[7];
    const float* bn      = (const float*)d_in[8];
    const float* Wg      = (const float*)d_in[9];
    const float* bg      = (const float*)d_in[10];
    const float* gamma   = (const float*)d_in[11];
    const float* beta    = (const float*)d_in[12];
    const float* W_att   = (const float*)d_in[13];
    const float* b_att   = (const float*)d_in[14];
    const float* W_score = (const float*)d_in[15];
    const float* b_score = (const float*)d_in[16];

    const int N = in_sizes[0] / 128;
    const int E = in_sizes[1];

    char* w = (char*)d_ws;
    auto alloc = [&](size_t bytes)->char* {
        char* p = w; w += (bytes + 255) & ~(size_t)255; return p;
    };
    u16* WT_in  = (u16*)alloc(128*128*2);
    u16* WT_att = (u16*)alloc(128*128*2);
    u16* WB     = (u16*)alloc(3*2*256*128*2);   // 3 layers x (WB1,WB2) fragment layout
    float* vb   = (float*)alloc(3*256*4);
    // zeroed region: cnt, notsink, nsink (contiguous)
    int* cnt      = (int*)alloc((size_t)N*4);
    int* notsink  = (int*)alloc((size_t)N*4);
    int* nsink    = (int*)alloc(256);
    size_t zero_bytes = (size_t)((char*)nsink + 256 - (char*)cnt);
    int* pos      = (int*)alloc((size_t)E*4);
    int* row_ptr  = (int*)alloc((size_t)N*4);
    int* blocksum = (int*)alloc(1024*4);
    int* csr_src  = (int*)alloc((size_t)E*4);
    float* inv_deg = (float*)alloc((size_t)N*4);
    float* haspred = (float*)alloc((size_t)N*4);
    int* sink_list = (int*)alloc((size_t)N*4);
    float* scores_sink = (float*)alloc((size_t)N*4);
    u16* buf0 = (u16*)alloc((size_t)N*128*2);   // h ping
    u16* buf1 = (u16*)alloc((size_t)N*128*2);   // h pong
    u16* bufn = (u16*)alloc((size_t)N*128*2);   // neigh

    float* h_out   = (float*)d_out;
    float* emb_out = h_out + (size_t)N*128;

    hipMemsetAsync(cnt, 0, zero_bytes, stream);

    k_wt_plain<<<512, 256, 0, stream>>>(W_in, W_att, Ws, Wn, WT_in, WT_att, WB);
    k_wt_comp<<<3*129, 256, 0, stream>>>(Ws, Wn, Wg, bs, bn, WB, vb);

    k_count<<<(E+255)/256, 256, 0, stream>>>(src, dst, cnt, notsink, pos, E);

    int nb = (N + 1023) / 1024;
    k_scan1<<<nb, 256, 0, stream>>>(cnt, blocksum, N);
    k_scan2<<<1, 256, 0, stream>>>(blocksum, nb);
    k_scan3<<<nb, 256, 0, stream>>>(cnt, blocksum, notsink, row_ptr, inv_deg, haspred,
                                    sink_list, nsink, N);
    k_place<<<(E+255)/256, 256, 0, stream>>>(src, dst, row_ptr, pos, csr_src, E);

    int gblk = (N + 63) / 64;
    int nblk = (N + 15) / 16;

    k_gemm_in<<<gblk, 256, 0, stream>>>(node_feats, WT_in, b_in, buf0, N);

    u16* hin = buf0;
    for (int i=0;i<3;i++){
        k_neigh<<<nblk, 256, 0, stream>>>(hin, row_ptr, cnt, inv_deg, csr_src, bufn, N);
        u16* hb  = (hin == buf0) ? buf1 : buf0;
        float* hf = (i == 2) ? h_out : nullptr;
        k_layer<<<gblk, 256, 0, stream>>>(hin, bufn,
                                          WB + (size_t)i*65536,
                                          bs + i*128, bn + i*128, bg + i*128,
                                          vb + i*256, vb + i*256 + 128,
                                          gamma + i*128, beta + i*128, haspred,
                                          hb, hf, N);
        hin = hb;
    }

    k_att_sink<<<8, 256, 0, stream>>>(h_out, WT_att, b_att, W_score, b_score,
                                      sink_list, nsink, scores_sink);
    k_pool_sink<<<1, 256, 0, stream>>>(h_out, sink_list, nsink, scores_sink, emb_out);

    (void)n_in; (void)out_size; (void)ws_size;
}

// Round 12
// 513.366 us; speedup vs baseline: 1.5469x; 1.0391x over previous
//
#include <hip/hip_runtime.h>
#include <cmath>

typedef unsigned short u16;
typedef unsigned int   u32;
typedef __attribute__((ext_vector_type(8))) short bf16x8;
typedef __attribute__((ext_vector_type(4))) float f32x4;
typedef __attribute__((ext_vector_type(4))) u32   u32x4;

__device__ __forceinline__ float bf2f(u16 u){
    union { u32 i; float f; } x; x.i = ((u32)u) << 16; return x.f;
}
__device__ __forceinline__ u16 f2bf(float f){
    union { float f; u32 i; } x; x.f = f;
    u32 r = x.i + 0x7fffu + ((x.i >> 16) & 1u);
    return (u16)(r >> 16);
}

// MFMA-fragment layout for composed layer weights WB (per layer, per mat 256x128):
//   element (n,k) -> tile t=n>>4, lane=((k>>3)&3)*16 + (n&15), slot kk=k>>5, e=k&7
//   linear u16 index: ((t*4 + kk)*64 + lane)*8 + e
// Stage s (0..7) of a layer = mat m=s>>2, tiles t = (s&3)*4 .. +3  -> contiguous 8192 u16.
__device__ __forceinline__ size_t frag_idx(int n, int k){
    int t = n >> 4, sl = n & 15, kk = k >> 5, g16 = (k >> 3) & 3, e = k & 7;
    return ((size_t)(t*4 + kk)*64 + g16*16 + sl)*8 + e;
}

// ---------------- graph preprocessing ----------------

__global__ void k_count(const int* __restrict__ src, const int* __restrict__ dst,
                        int* cnt, int* notsink, int* pos, int E){
    int e = blockIdx.x*256 + threadIdx.x;
    if (e < E){
        pos[e] = atomicAdd(&cnt[dst[e]], 1);
        notsink[src[e]] = 1;   // benign race: all writers store 1
    }
}

__global__ void k_scan1(const int* __restrict__ in, int* blocksum, int N){
    __shared__ int sh[256];
    int tid = threadIdx.x;
    int base = blockIdx.x*1024 + tid*4;
    int s = 0;
    for (int j=0;j<4;j++){ int i = base+j; s += (i < N) ? in[i] : 0; }
    sh[tid] = s; __syncthreads();
    for (int d=128; d>0; d>>=1){ if (tid < d) sh[tid] += sh[tid+d]; __syncthreads(); }
    if (tid == 0) blocksum[blockIdx.x] = sh[0];
}

__global__ void k_scan2(int* blocksum, int nb){
    if (threadIdx.x == 0){
        int run = 0;
        for (int i=0;i<nb;i++){ int v = blocksum[i]; blocksum[i] = run; run += v; }
    }
}

// scan3 + sink compaction (order nondeterministic; softmax pool is order-invariant)
__global__ void k_scan3(const int* __restrict__ in, const int* __restrict__ blockoff,
                        const int* __restrict__ notsink,
                        int* out, float* inv_deg, float* haspred,
                        int* sink_list, int* nsink, int N){
    __shared__ int sh[256];
    int tid = threadIdx.x;
    int base = blockIdx.x*1024 + tid*4;
    int e[4]; int s = 0;
    for (int j=0;j<4;j++){ int i = base+j; e[j] = (i < N) ? in[i] : 0; s += e[j]; }
    sh[tid] = s; __syncthreads();
    for (int d=1; d<256; d<<=1){
        int t = (tid >= d) ? sh[tid-d] : 0;
        __syncthreads();
        sh[tid] += t;
        __syncthreads();
    }
    int excl = sh[tid] - s + blockoff[blockIdx.x];
    for (int j=0;j<4;j++){
        int i = base+j;
        if (i < N){
            out[i] = excl; excl += e[j];
            inv_deg[i] = 1.0f / (float)(e[j] > 1 ? e[j] : 1);
            haspred[i] = e[j] > 0 ? 1.0f : 0.0f;
            if (notsink[i] == 0){
                int p = atomicAdd(nsink, 1);
                sink_list[p] = i;
            }
        }
    }
}

__global__ void k_place(const int* __restrict__ src, const int* __restrict__ dst,
                        const int* __restrict__ row_ptr, const int* __restrict__ pos,
                        int* csr_src, int E){
    int e = blockIdx.x*256 + threadIdx.x;
    if (e < E)
        csr_src[row_ptr[dst[e]] + pos[e]] = src[e];
}

// ---------------- weight prep ----------------
// WT_in / WT_att: f32 [k][n] -> bf16 [n][k]. WB plain halves in fragment layout.
__global__ void k_wt_plain(const float* __restrict__ W_in, const float* __restrict__ W_att,
                           const float* __restrict__ Ws, const float* __restrict__ Wn,
                           u16* WT_in, u16* WT_att, u16* WB){
    int i = blockIdx.x*256 + threadIdx.x;   // [0, 131072)
    if (i < 32768){
        const float* srcm = (i < 16384) ? W_in : W_att;
        u16* dstm = (i < 16384) ? WT_in : WT_att;
        int w = i & 16383, n = w >> 7, k = w & 127;
        dstm[n*128 + k] = f2bf(srcm[k*128 + n]);
    } else {
        int off = i - 32768;                 // [0, 98304)
        int m  = off / 49152;                // 0: from Ws, 1: from Wn
        int w  = off % 49152;
        int l  = w >> 14, ww = w & 16383;
        int n  = ww >> 7, k = ww & 127;
        const float* srcm = m ? Wn : Ws;
        u16* dstm = WB + ((size_t)l*2 + m)*32768;
        dstm[frag_idx(n, k)] = f2bf(srcm[(size_t)l*16384 + k*128 + n]);
    }
}

// Composite halves (cols 128..255) + bias composites vb1 = bs@Wg_bot, vb2 = bn@Wg_bot.
__global__ void k_wt_comp(const float* __restrict__ Ws, const float* __restrict__ Wn,
                          const float* __restrict__ Wg,
                          const float* __restrict__ bs, const float* __restrict__ bn,
                          u16* WB, float* vb){
    __shared__ float cols[2][128];
    int l = blockIdx.x / 129;
    int b = blockIdx.x % 129;
    const float* Wgb = Wg + (size_t)l*32768 + 16384;   // Wg_bot [128][128]
    int tid = threadIdx.x;
    if (b == 128){
        int n = tid & 127;
        const float* bv = (tid < 128) ? (bs + l*128) : (bn + l*128);
        float acc = 0.f;
        for (int j=0;j<128;j++) acc += bv[j] * Wgb[j*128 + n];
        vb[l*256 + (tid>>7)*128 + n] = acc;
        return;
    }
    int m  = b >> 6;            // 0: from Ws, 1: from Wn
    int n0 = (b & 63) * 2;
    int nn = tid >> 7, k = tid & 127;
    cols[tid>>7][tid&127] = Wgb[(size_t)(tid&127)*128 + n0 + (tid>>7)];
    __syncthreads();
    const float* A = (m ? Wn : Ws) + (size_t)l*16384;
    float acc = 0.f;
    for (int j=0;j<128;j++) acc += A[k*128 + j] * cols[nn][j];
    int n = n0 + nn;
    if (m == 0) acc += Wg[(size_t)l*32768 + k*128 + n];
    u16* dstm = WB + ((size_t)l*2 + m)*32768;
    dstm[frag_idx(128 + n, k)] = f2bf(acc);
}

// ---------------- neighbor mean: 4 nodes/wave, 16 lanes x 16B per row ----------------
// Node order REVERSED: high-index nodes have the highest expected in-degree
// (E[deg(d)] ~ 8 ln(N/(N-d)) for this DAG family), so mapping them to the FIRST
// blocks lets the long-running blocks start at t=0 and overlap the thousands of
// short ones, instead of running on a draining device (tail imbalance).

__global__ void k_neigh(const u16* __restrict__ h, const int* __restrict__ row_ptr,
                        const int* __restrict__ indeg, const float* __restrict__ inv_deg,
                        const int* __restrict__ csr_src, u16* __restrict__ neigh, int N){
    int wid  = (blockIdx.x*256 + threadIdx.x) >> 6;
    int nwid = gridDim.x * 4;            // total waves (= node-group capacity)
    int lane = threadIdx.x & 63;
    int sub = lane >> 4, sl = lane & 15;
    int wr  = nwid - 1 - wid;            // reversed node-group
    int node = wr*4 + sub;
    bool valid = node < N;
    int deg   = valid ? indeg[node]   : 0;
    int start = valid ? row_ptr[node] : 0;
    float acc[8] = {0.f,0.f,0.f,0.f,0.f,0.f,0.f,0.f};
    for (int e0 = 0; __any(e0 < deg); e0 += 16){
        int idx = 0;
        if (e0 + sl < deg) idx = csr_src[start + e0 + sl];
        int cnt = deg - e0;
        #pragma unroll
        for (int j = 0; j < 16; j++){
            int sidx = __shfl(idx, (sub << 4) | j);
            if (j < cnt){
                bf16x8 v = *(const bf16x8*)(h + (size_t)sidx*128 + sl*8);
                #pragma unroll
                for (int t=0;t<8;t++) acc[t] += bf2f((u16)v[t]);
            }
        }
    }
    if (valid){
        float iv = inv_deg[node];
        u16 o[8];
        #pragma unroll
        for (int t=0;t<8;t++) o[t] = f2bf(acc[t]*iv);
        *(u32x4*)(neigh + (size_t)node*128 + sl*8) = *(const u32x4*)o;
    }
}

// ---------------- shared GEMM tile machinery ----------------

__device__ __forceinline__ void stage_A_f32(const float* __restrict__ A, u16 (*lA)[136],
                                            int row0, int n_rows, int tid){
    #pragma unroll
    for (int i=0;i<4;i++){
        int c = i*256 + tid;
        int r = c >> 4, col8 = (c & 15) * 8;
        u16 o[8] = {0,0,0,0,0,0,0,0};
        if (row0 + r < n_rows){
            float4 v0 = *(const float4*)(A + (size_t)(row0 + r)*128 + col8);
            float4 v1 = *(const float4*)(A + (size_t)(row0 + r)*128 + col8 + 4);
            o[0]=f2bf(v0.x); o[1]=f2bf(v0.y); o[2]=f2bf(v0.z); o[3]=f2bf(v0.w);
            o[4]=f2bf(v1.x); o[5]=f2bf(v1.y); o[6]=f2bf(v1.z); o[7]=f2bf(v1.w);
        }
        *(u32x4*)&lA[r][col8] = *(const u32x4*)o;
    }
}

__device__ __forceinline__ void stage_B(const u16* __restrict__ BT, int Ks, int koff0,
                                        u16 (*lB)[136], int tid){
    #pragma unroll
    for (int i=0;i<8;i++){
        int c = i*256 + tid;
        int n = c >> 4, col8 = (c & 15) * 8;
        u32x4 v = *(const u32x4*)(BT + (size_t)n*Ks + koff0 + col8);
        *(u32x4*)&lB[n][col8] = v;
    }
}

__device__ __forceinline__ void mfma_tile(const u16 (*lA)[136], const u16 (*lB)[136],
                                          int wave, int lane, f32x4* acc){
    #pragma unroll
    for (int kk=0;kk<4;kk++){
        int koff = kk*32 + (lane >> 4) * 8;
        bf16x8 a = *(const bf16x8*)&lA[wave*16 + (lane & 15)][koff];
        #pragma unroll
        for (int t=0;t<8;t++){
            bf16x8 b = *(const bf16x8*)&lB[t*16 + (lane & 15)][koff];
            acc[t] = __builtin_amdgcn_mfma_f32_16x16x32_bf16(a, b, acc[t], 0, 0, 0);
        }
    }
}

// ---------------- GEMM: h0 = f32 feats @ W_in + b_in -> bf16 ----------------
// Output vectorized via lA round-trip (transpose write is a 2-way bank alias = free).

__global__ __launch_bounds__(256) void k_gemm_in(
    const float* __restrict__ A, const u16* __restrict__ BT,
    const float* __restrict__ bias, u16* __restrict__ C, int n_rows)
{
    __shared__ u16 lA[64][136];
    __shared__ u16 lB[128][136];
    int tid = threadIdx.x, wave = tid >> 6, lane = tid & 63;
    int row0 = blockIdx.x * 64;
    f32x4 acc[8];
    #pragma unroll
    for (int t=0;t<8;t++) acc[t] = (f32x4){0.f,0.f,0.f,0.f};
    stage_A_f32(A, lA, row0, n_rows, tid);
    stage_B(BT, 128, 0, lB, tid);
    __syncthreads();
    mfma_tile(lA, lB, wave, lane, acc);

    int sl = lane & 15;
    int rbase = wave*16 + (lane >> 4)*4;
    float bc[8];
    #pragma unroll
    for (int t=0;t<8;t++) bc[t] = bias[t*16 + sl];
    __syncthreads();   // all lA reads (mfma) complete before overwrite
    #pragma unroll
    for (int r=0;r<4;r++)
        #pragma unroll
        for (int t=0;t<8;t++)
            lA[rbase + r][t*16 + sl] = f2bf(acc[t][r] + bc[t]);
    __syncthreads();
    #pragma unroll
    for (int i=0;i<4;i++){
        int c = i*256 + tid;
        int r = c >> 4, col8 = (c & 15) * 8;
        if (row0 + r < n_rows)
            *(u32x4*)&C[(size_t)(row0 + r)*128 + col8] = *(const u32x4*)&lA[r][col8];
    }
}

// -------- fused layer (round-3 proven structure), composed single-GEMM, --------
// -------- pipelined LDS-staged B; output: f32-only (last) / vectorized bf16 ----

__global__ __launch_bounds__(256, 3) void k_layer(
    const u16* __restrict__ H, const u16* __restrict__ Ng,
    const u16* __restrict__ WB,                       // layer's 8 stages x 8192 u16
    const float* __restrict__ bs, const float* __restrict__ bn,
    const float* __restrict__ bg,
    const float* __restrict__ vb1, const float* __restrict__ vb2,
    const float* __restrict__ gamma, const float* __restrict__ beta,
    const float* __restrict__ haspred,
    u16* __restrict__ Hb, float* __restrict__ Hf, int n_rows)
{
    __shared__ u16 lH[64][132];       // h tile for epilogue blend (padded: conflict-free)
    __shared__ u16 lB[2][8192];       // B fragment double buffer (16KB each)
    int tid = threadIdx.x, wave = tid >> 6, lane = tid & 63;
    int sl = lane & 15, g16 = lane >> 4;
    int row0 = blockIdx.x * 64;

    // A fragments in registers: row = wave*16+sl, k = kk*32 + g16*8 + 0..7
    int arow = row0 + wave*16 + sl;
    bool av = arow < n_rows;
    bf16x8 a1[4], a2[4];
    #pragma unroll
    for (int kk=0;kk<4;kk++){
        a1[kk] = (bf16x8){0,0,0,0,0,0,0,0};
        a2[kk] = (bf16x8){0,0,0,0,0,0,0,0};
    }
    if (av){
        #pragma unroll
        for (int kk=0;kk<4;kk++){
            a1[kk] = *(const bf16x8*)(H  + (size_t)arow*128 + kk*32 + g16*8);
            a2[kk] = *(const bf16x8*)(Ng + (size_t)arow*128 + kk*32 + g16*8);
        }
    }

    // stage h tile for epilogue
    #pragma unroll
    for (int i=0;i<4;i++){
        int c = i*256 + tid;
        int r = c >> 4, col8 = (c & 15) * 8;
        u32x4 v = {0,0,0,0};
        if (row0 + r < n_rows)
            v = *(const u32x4*)(H + (size_t)(row0 + r)*128 + col8);
        *(u32x4*)&lH[r][col8] = v;
    }

    // stage 0 of B
    u32x4 st[4];
    #pragma unroll
    for (int i=0;i<4;i++)
        st[i] = *(const u32x4*)(WB + (size_t)(i*256 + tid)*8);
    #pragma unroll
    for (int i=0;i<4;i++)
        *(u32x4*)&lB[0][(i*256 + tid)*8] = st[i];

    f32x4 acc[16];
    #pragma unroll
    for (int t=0;t<16;t++) acc[t] = (f32x4){0.f,0.f,0.f,0.f};
    __syncthreads();

    // 8 stages: s<4 use a1 (h), s>=4 use a2 (ng); stage s covers col-tiles (s&3)*4..+3
    #pragma unroll
    for (int s=0;s<8;s++){
        int cur = s & 1;
        if (s < 7){
            const u16* sp = WB + (size_t)(s+1)*8192;
            #pragma unroll
            for (int i=0;i<4;i++)
                st[i] = *(const u32x4*)(sp + (size_t)(i*256 + tid)*8);
        }
        const u16* bp = &lB[cur][lane*8];
        #pragma unroll
        for (int j=0;j<4;j++){
            #pragma unroll
            for (int kk=0;kk<4;kk++){
                bf16x8 b = *(const bf16x8*)(bp + ((j*4 + kk) << 9));
                int ai = (s & 3)*4 + j;
                acc[ai] = __builtin_amdgcn_mfma_f32_16x16x32_bf16(
                    (s >= 4) ? a2[kk] : a1[kk], b, acc[ai], 0, 0, 0);
            }
        }
        if (s < 7){
            #pragma unroll
            for (int i=0;i<4;i++)
                *(u32x4*)&lB[cur ^ 1][(i*256 + tid)*8] = st[i];
        }
        __syncthreads();
    }

    // epilogue: gate, blend, LayerNorm, ReLU
    int rbase = wave*16 + g16*4;
    float bM[8], bnl[8], bG[8], vb2l[8], gam[8], bet[8];
    #pragma unroll
    for (int t=0;t<8;t++){
        int c = t*16 + sl;
        bM[t] = bs[c]; bnl[t] = bn[c];
        bG[t] = bg[c] + vb1[c]; vb2l[t] = vb2[c];
        gam[t] = gamma[c]; bet[t] = beta[c];
    }
    if (Hf){
        // last layer: f32 output only (full 64B lines per (r,t) store)
        for (int r=0;r<4;r++){
            int row = row0 + rbase + r;
            if (row >= n_rows) continue;   // quad-uniform
            float hp = haspred[row];
            float v[8], s = 0.f;
            #pragma unroll
            for (int t=0;t<8;t++){
                int c = t*16 + sl;
                float m = acc[t][r]   + bM[t] + hp*bnl[t];
                float x = acc[t+8][r] + bG[t] + hp*vb2l[t];
                float gg = 1.f/(1.f + expf(-x));
                float hv = bf2f(lH[rbase + r][c]);
                v[t] = gg*m + (1.f - gg)*hv;
                s += v[t];
            }
            s += __shfl_xor(s,1); s += __shfl_xor(s,2); s += __shfl_xor(s,4); s += __shfl_xor(s,8);
            float mu = s * (1.f/128.f);
            float q = 0.f;
            #pragma unroll
            for (int t=0;t<8;t++){ float d = v[t]-mu; q += d*d; }
            q += __shfl_xor(q,1); q += __shfl_xor(q,2); q += __shfl_xor(q,4); q += __shfl_xor(q,8);
            float rs = rsqrtf(q*(1.f/128.f) + 1e-5f);
            #pragma unroll
            for (int t=0;t<8;t++){
                float o = (v[t]-mu)*rs*gam[t] + bet[t];
                Hf[(size_t)row*128 + t*16 + sl] = o > 0.f ? o : 0.f;
            }
        }
    } else {
        // intermediate layer: bf16 output, vectorized via lH round-trip
        float ov[4][8];
        for (int r=0;r<4;r++){
            int row = row0 + rbase + r;
            float hp = (row < n_rows) ? haspred[row] : 0.f;
            float v[8], s = 0.f;
            #pragma unroll
            for (int t=0;t<8;t++){
                int c = t*16 + sl;
                float m = acc[t][r]   + bM[t] + hp*bnl[t];
                float x = acc[t+8][r] + bG[t] + hp*vb2l[t];
                float gg = 1.f/(1.f + expf(-x));
                float hv = bf2f(lH[rbase + r][c]);
                v[t] = gg*m + (1.f - gg)*hv;
                s += v[t];
            }
            s += __shfl_xor(s,1); s += __shfl_xor(s,2); s += __shfl_xor(s,4); s += __shfl_xor(s,8);
            float mu = s * (1.f/128.f);
            float q = 0.f;
            #pragma unroll
            for (int t=0;t<8;t++){ float d = v[t]-mu; q += d*d; }
            q += __shfl_xor(q,1); q += __shfl_xor(q,2); q += __shfl_xor(q,4); q += __shfl_xor(q,8);
            float rs = rsqrtf(q*(1.f/128.f) + 1e-5f);
            #pragma unroll
            for (int t=0;t<8;t++){
                float o = (v[t]-mu)*rs*gam[t] + bet[t];
                ov[r][t] = o > 0.f ? o : 0.f;
            }
        }
        __syncthreads();   // all lH blend-reads complete
        #pragma unroll
        for (int r=0;r<4;r++)
            #pragma unroll
            for (int t=0;t<8;t++)
                lH[rbase + r][t*16 + sl] = f2bf(ov[r][t]);
        __syncthreads();
        #pragma unroll
        for (int i=0;i<4;i++){
            int c = i*256 + tid;
            int r = c >> 4, col8 = (c & 15) * 8;
            if (row0 + r < n_rows)
                *(u32x4*)&Hb[(size_t)(row0 + r)*128 + col8] = *(const u32x4*)&lH[r][col8];
        }
    }
}

// ------- attention scores on SINK ROWS ONLY (h read as f32 from d_out) -------

__global__ __launch_bounds__(256) void k_att_sink(
    const float* __restrict__ Hf, const u16* __restrict__ BT,
    const float* __restrict__ b_att, const float* __restrict__ Wsc,
    const float* __restrict__ bsc, const int* __restrict__ sink_list,
    const int* __restrict__ nsink, float* __restrict__ scores_sink)
{
    __shared__ u16 lA[64][136];
    __shared__ u16 lB[128][136];
    int ns = *nsink;
    int tid = threadIdx.x, wave = tid >> 6, lane = tid & 63;
    int sl = lane & 15;
    stage_B(BT, 128, 0, lB, tid);
    float bac[8], wc[8];
    #pragma unroll
    for (int t=0;t<8;t++){ bac[t] = b_att[t*16 + sl]; wc[t] = Wsc[t*16 + sl]; }
    float b0 = bsc[0];
    int rbase = wave*16 + (lane >> 4)*4;

    for (int c0 = blockIdx.x*64; c0 < ns; c0 += gridDim.x*64){
        __syncthreads();   // lA reuse fence (also covers initial lB stage)
        #pragma unroll
        for (int i=0;i<4;i++){
            int c = i*256 + tid;
            int r = c >> 4, col8 = (c & 15) * 8;
            u16 o[8] = {0,0,0,0,0,0,0,0};
            if (c0 + r < ns){
                int row = sink_list[c0 + r];
                float4 v0 = *(const float4*)(Hf + (size_t)row*128 + col8);
                float4 v1 = *(const float4*)(Hf + (size_t)row*128 + col8 + 4);
                o[0]=f2bf(v0.x); o[1]=f2bf(v0.y); o[2]=f2bf(v0.z); o[3]=f2bf(v0.w);
                o[4]=f2bf(v1.x); o[5]=f2bf(v1.y); o[6]=f2bf(v1.z); o[7]=f2bf(v1.w);
            }
            *(u32x4*)&lA[r][col8] = *(const u32x4*)o;
        }
        __syncthreads();
        f32x4 acc[8];
        #pragma unroll
        for (int t=0;t<8;t++) acc[t] = (f32x4){0.f,0.f,0.f,0.f};
        mfma_tile(lA, lB, wave, lane, acc);

        for (int r=0;r<4;r++){
            int i = c0 + rbase + r;
            if (i >= ns) continue;
            float p = 0.f;
            #pragma unroll
            for (int t=0;t<8;t++) p += tanhf(acc[t][r] + bac[t]) * wc[t];
            p += __shfl_xor(p,1); p += __shfl_xor(p,2); p += __shfl_xor(p,4); p += __shfl_xor(p,8);
            if (sl == 0)
                scores_sink[i] = p + b0;
        }
    }
}

// ------------- softmax-pool over compacted sinks (h read as f32) -------------

__global__ void k_pool_sink(const float* __restrict__ Hf, const int* __restrict__ sink_list,
                            const int* __restrict__ nsink,
                            const float* __restrict__ scores_sink,
                            float* __restrict__ out){
    __shared__ float sh[256];
    __shared__ float swg[2];
    int ns = *nsink;
    int tid = threadIdx.x;
    int col = tid & 127, grp = tid >> 7;
    float acc = 0.f, wsum = 0.f;
    for (int i = grp; i < ns; i += 2){
        float w = expf(scores_sink[i]);
        acc += w * Hf[(size_t)sink_list[i]*128 + col];
        if (col == 0) wsum += w;
    }
    sh[tid] = acc;
    if (col == 0) swg[grp] = wsum;
    __syncthreads();
    if (tid < 128) out[tid] = (sh[tid] + sh[tid+128]) / (swg[0] + swg[1]);
}

// ---------------- host launch ----------------

extern "C" void kernel_launch(void* const* d_in, const int* in_sizes, int n_in,
                              void* d_out, int out_size, void* d_ws, size_t ws_size,
                              hipStream_t stream)
{
    const float* node_feats = (const float*)d_in[0];
    const int* src     = (const int*)d_in[1];
    const int* dst     = (const int*)d_in[2];
    const float* W_in    = (const float*)d_in[3];
    const float* b_in    = (const float*)d_in[4];
    const float* Ws      = (const float*)d_in[5];
    const float* bs      = (const float*)d_in[6];
    const float* Wn      = (const float*)d_in[7];
    const float* bn      = (const float*)d_in[8];
    const float* Wg      = (const float*)d_in[9];
    const float* bg      = (const float*)d_in[10];
    const float* gamma   = (const float*)d_in[11];
    const float* beta    = (const float*)d_in[12];
    const float* W_att   = (const float*)d_in[13];
    const float* b_att   = (const float*)d_in[14];
    const float* W_score = (const float*)d_in[15];
    const float* b_score = (const float*)d_in[16];

    const int N = in_sizes[0] / 128;
    const int E = in_sizes[1];

    char* w = (char*)d_ws;
    auto alloc = [&](size_t bytes)->char* {
        char* p = w; w += (bytes + 255) & ~(size_t)255; return p;
    };
    u16* WT_in  = (u16*)alloc(128*128*2);
    u16* WT_att = (u16*)alloc(128*128*2);
    u16* WB     = (u16*)alloc(3*2*256*128*2);   // 3 layers x (WB1,WB2) fragment layout
    float* vb   = (float*)alloc(3*256*4);
    // zeroed region: cnt, notsink, nsink (contiguous)
    int* cnt      = (int*)alloc((size_t)N*4);
    int* notsink  = (int*)alloc((size_t)N*4);
    int* nsink    = (int*)alloc(256);
    size_t zero_bytes = (size_t)((char*)nsink + 256 - (char*)cnt);
    int* pos      = (int*)alloc((size_t)E*4);
    int* row_ptr  = (int*)alloc((size_t)N*4);
    int* blocksum = (int*)alloc(1024*4);
    int* csr_src  = (int*)alloc((size_t)E*4);
    float* inv_deg = (float*)alloc((size_t)N*4);
    float* haspred = (float*)alloc((size_t)N*4);
    int* sink_list = (int*)alloc((size_t)N*4);
    float* scores_sink = (float*)alloc((size_t)N*4);
    u16* buf0 = (u16*)alloc((size_t)N*128*2);   // h ping
    u16* buf1 = (u16*)alloc((size_t)N*128*2);   // h pong
    u16* bufn = (u16*)alloc((size_t)N*128*2);   // neigh

    float* h_out   = (float*)d_out;
    float* emb_out = h_out + (size_t)N*128;

    hipMemsetAsync(cnt, 0, zero_bytes, stream);

    k_wt_plain<<<512, 256, 0, stream>>>(W_in, W_att, Ws, Wn, WT_in, WT_att, WB);
    k_wt_comp<<<3*129, 256, 0, stream>>>(Ws, Wn, Wg, bs, bn, WB, vb);

    k_count<<<(E+255)/256, 256, 0, stream>>>(src, dst, cnt, notsink, pos, E);

    int nb = (N + 1023) / 1024;
    k_scan1<<<nb, 256, 0, stream>>>(cnt, blocksum, N);
    k_scan2<<<1, 256, 0, stream>>>(blocksum, nb);
    k_scan3<<<nb, 256, 0, stream>>>(cnt, blocksum, notsink, row_ptr, inv_deg, haspred,
                                    sink_list, nsink, N);
    k_place<<<(E+255)/256, 256, 0, stream>>>(src, dst, row_ptr, pos, csr_src, E);

    int gblk = (N + 63) / 64;
    int nblk = (N + 15) / 16;

    k_gemm_in<<<gblk, 256, 0, stream>>>(node_feats, WT_in, b_in, buf0, N);

    u16* hin = buf0;
    for (int i=0;i<3;i++){
        k_neigh<<<nblk, 256, 0, stream>>>(hin, row_ptr, cnt, inv_deg, csr_src, bufn, N);
        u16* hb  = (hin == buf0) ? buf1 : buf0;
        float* hf = (i == 2) ? h_out : nullptr;
        k_layer<<<gblk, 256, 0, stream>>>(hin, bufn,
                                          WB + (size_t)i*65536,
                                          bs + i*128, bn + i*128, bg + i*128,
                                          vb + i*256, vb + i*256 + 128,
                                          gamma + i*128, beta + i*128, haspred,
                                          hb, hf, N);
        hin = hb;
    }

    k_att_sink<<<8, 256, 0, stream>>>(h_out, WT_att, b_att, W_score, b_score,
                                      sink_list, nsink, scores_sink);
    k_pool_sink<<<1, 256, 0, stream>>>(h_out, sink_list, nsink, scores_sink, emb_out);

    (void)n_in; (void)out_size; (void)ws_size;
}